// Round 10
// baseline (166.544 us; speedup 1.0000x reference)
//
#include <hip/hip_runtime.h>
#include <math.h>

#define EPS 1e-8f
#define NN 65536
#define MAGIC 1.0f

// ws float offsets
#define WS_GATES 0       // 2048
#define WS_HNEW  2048    // 512
#define WS_ROUT  2560    // 518 (pad 520)
#define WS_PMAX  3104    // 2048
#define WS_PEXP  5152    // 2048
#define WS_S     7200    // 65536
#define WS_PSUM  72736   // 256
#define WS_PART  72992   // 256*512 = 131072
#define WS_FLAGG 204064  // 128 gate-block flags
#define WS_FLAGP 204192  // 256 part-block flags
#define WS_BF    262144  // bf16 shadow of memory: 65536*512*2B = 64 MB (as shorts)

__device__ __forceinline__ float wave_sum(float v) {
    for (int o = 32; o > 0; o >>= 1) v += __shfl_xor(v, o);
    return v;
}
__device__ __forceinline__ float sigm(float x) { return 1.f / (1.f + expf(-x)); }
__device__ __forceinline__ float softplusf_(float x) {
    return x > 20.f ? x : log1pf(expf(x));
}
__device__ __forceinline__ float dot4(float4 a, float4 b) {
    return a.x * b.x + a.y * b.y + a.z * b.z + a.w * b.w;
}
__device__ __forceinline__ float4 ld4(const float* p) { return *(const float4*)p; }

// agent-scope coherent accessors (R6/R8-proven on this chip)
__device__ __forceinline__ float ald(const float* p) {
    return __hip_atomic_load(p, __ATOMIC_RELAXED, __HIP_MEMORY_SCOPE_AGENT);
}
__device__ __forceinline__ float ald_acq(const float* p) {
    return __hip_atomic_load(p, __ATOMIC_ACQUIRE, __HIP_MEMORY_SCOPE_AGENT);
}
__device__ __forceinline__ void ast(float* p, float v) {
    __hip_atomic_store(p, v, __ATOMIC_RELAXED, __HIP_MEMORY_SCOPE_AGENT);
}
__device__ __forceinline__ void ast_rel(float* p, float v) {
    __hip_atomic_store(p, v, __ATOMIC_RELEASE, __HIP_MEMORY_SCOPE_AGENT);
}
__device__ __forceinline__ float2 ald2(const float* p) {
    unsigned long long u = __hip_atomic_load((const unsigned long long*)p,
        __ATOMIC_RELAXED, __HIP_MEMORY_SCOPE_AGENT);
    float2 r; __builtin_memcpy(&r, &u, 8); return r;
}
__device__ __forceinline__ void ast2(float* p, float2 v) {
    unsigned long long u; __builtin_memcpy(&u, &v, 8);
    __hip_atomic_store((unsigned long long*)p, u,
        __ATOMIC_RELAXED, __HIP_MEMORY_SCOPE_AGENT);
}

// pack two floats as RNE bf16 into one uint (a low short, b high short)
__device__ __forceinline__ unsigned bf2(float a, float b) {
    unsigned ua = __float_as_uint(a), ub = __float_as_uint(b);
    unsigned ra = (ua + 0x7FFFu + ((ua >> 16) & 1u)) >> 16;
    unsigned rb = (ub + 0x7FFFu + ((ub >> 16) & 1u)) >> 16;
    return ra | (rb << 16);
}

// K1: gates (blocks 0-127, 16 rows each) -> per-block flag -> h_new + r_out
__global__ __launch_bounds__(256) void k_front(const float* __restrict__ x,
                                               const float* __restrict__ pr,
                                               const float* __restrict__ h,
                                               const float* __restrict__ c,
                                               const float* __restrict__ W_ih,
                                               const float* __restrict__ b_ih,
                                               const float* __restrict__ W_hh,
                                               const float* __restrict__ b_hh,
                                               const float* __restrict__ W_read,
                                               const float* __restrict__ b_read,
                                               float* __restrict__ ws) {
    const int b = blockIdx.x, t = threadIdx.x;
    const int lane = t & 63, wv = t >> 6;
    __shared__ float sh[512];

    if (b < 128) {
        #pragma unroll
        for (int i = 0; i < 4; ++i) {
            const int row = b * 16 + wv * 4 + i;
            const float* wi = W_ih + (size_t)row * 768;
            const float* wh = W_hh + (size_t)row * 512;
            float acc = dot4(ld4(wi + lane * 4), ld4(x + lane * 4))
                      + dot4(ld4(wi + 256 + lane * 4), ld4(pr + lane * 4))
                      + dot4(ld4(wi + 512 + lane * 4), ld4(pr + 256 + lane * 4))
                      + dot4(ld4(wh + lane * 4), ld4(h + lane * 4))
                      + dot4(ld4(wh + 256 + lane * 4), ld4(h + 256 + lane * 4));
            acc = wave_sum(acc);
            if (lane == 0) ast(ws + WS_GATES + row, acc + b_ih[row] + b_hh[row]);
        }
        __syncthreads();
        if (t == 0) ast_rel(ws + WS_FLAGG + b, MAGIC);
    }

    if (wv == 0) {
        int cap = 0;
        for (;;) {
            float v0 = ald_acq(ws + WS_FLAGG + lane);
            float v1 = ald_acq(ws + WS_FLAGG + 64 + lane);
            if (__all(v0 == MAGIC && v1 == MAGIC)) break;
            __builtin_amdgcn_s_sleep(1);
            if (++cap > (1 << 20)) break;
        }
    }
    __syncthreads();

    for (int j = t; j < 512; j += 256) {
        float ig = ald(ws + WS_GATES + j);
        float fg = ald(ws + WS_GATES + 512 + j);
        float gg = ald(ws + WS_GATES + 1024 + j);
        float og = ald(ws + WS_GATES + 1536 + j);
        float cn = sigm(fg) * c[j] + sigm(ig) * tanhf(gg);
        float hn = sigm(og) * tanhf(cn);
        sh[j] = hn;
        if (b == 0) ws[WS_HNEW + j] = hn;
    }
    __syncthreads();
    const int o = b * 4 + wv;
    if (o < 518) {
        const float* wr = W_read + (size_t)o * 512;
        float acc = dot4(ld4(wr + lane * 4), ld4(sh + lane * 4))
                  + dot4(ld4(wr + 256 + lane * 4), ld4(sh + 256 + lane * 4));
        acc = wave_sum(acc);
        if (lane == 0) ws[WS_ROUT + o] = acc + b_read[o];
    }
}

// K2: cosine scores + bf16 shadow write (row already in registers)
__global__ __launch_bounds__(256) void k_cos(const float* __restrict__ mem,
                                             float* __restrict__ ws) {
    const int t = threadIdx.x, lane = t & 63, wv = t >> 6;
    const int gw = blockIdx.x * 4 + wv;
    const float* key = ws + WS_ROUT;
    unsigned short* wsb = (unsigned short*)(ws + WS_BF);
    float4 ka = ld4(key + lane * 4);
    float4 kb = ld4(key + 256 + lane * 4);
    ka.x += EPS; ka.y += EPS; ka.z += EPS; ka.w += EPS;
    kb.x += EPS; kb.y += EPS; kb.z += EPS; kb.w += EPS;
    float kq = wave_sum(dot4(ka, ka) + dot4(kb, kb));
    const float nb = fmaxf(sqrtf(kq), EPS);
    const float beta = softplusf_(key[512]);
    float* sp = ws + WS_S;
    float m = -1e30f, e = 0.f;
    for (int n = gw; n < NN; n += 8192) {
        float4 va = ld4(mem + (size_t)n * 512 + lane * 4);
        float4 vb = ld4(mem + (size_t)n * 512 + 256 + lane * 4);
        // bf16 shadow of the RAW row (before EPS)
        uint2 p0 = make_uint2(bf2(va.x, va.y), bf2(va.z, va.w));
        uint2 p1 = make_uint2(bf2(vb.x, vb.y), bf2(vb.z, vb.w));
        *(uint2*)(wsb + (size_t)n * 512 + lane * 4) = p0;
        *(uint2*)(wsb + (size_t)n * 512 + 256 + lane * 4) = p1;
        va.x += EPS; va.y += EPS; va.z += EPS; va.w += EPS;
        vb.x += EPS; vb.y += EPS; vb.z += EPS; vb.w += EPS;
        float dot = dot4(va, ka) + dot4(vb, kb);
        float sq  = dot4(va, va) + dot4(vb, vb);
        for (int o = 32; o > 0; o >>= 1) {
            dot += __shfl_xor(dot, o);
            sq  += __shfl_xor(sq, o);
        }
        float na = fmaxf(sqrtf(sq), EPS);
        float sv = beta * dot / (na * nb);
        if (lane == 0) sp[n] = sv;
        float nm = fmaxf(m, sv);
        e = e * expf(m - nm) + expf(sv - nm);
        m = nm;
    }
    __shared__ float sm[4], se[4];
    if (lane == 0) { sm[wv] = m; se[wv] = e; }
    __syncthreads();
    if (t == 0) {
        float M = fmaxf(fmaxf(sm[0], sm[1]), fmaxf(sm[2], sm[3]));
        float E = se[0] * expf(sm[0] - M) + se[1] * expf(sm[1] - M) +
                  se[2] * expf(sm[2] - M) + se[3] * expf(sm[3] - M);
        ws[WS_PMAX + blockIdx.x] = M;
        ws[WS_PEXP + blockIdx.x] = E;
    }
}

// K3: stats + p + bf16 partial column sums -> flag -> blocks 0..31 output phase
__global__ __launch_bounds__(512) void k_readout(const float* __restrict__ rs,
                                                 const float* __restrict__ W_out,
                                                 const float* __restrict__ b_out,
                                                 float* __restrict__ ws,
                                                 float* __restrict__ out) {
    const int b = blockIdx.x, t = threadIdx.x;
    const int lane = t & 63, wv = t >> 6;
    __shared__ float s_m[8], s_e[8];
    __shared__ float wi_l[258];
    __shared__ float pl[256];
    __shared__ float s_ps[4];
    __shared__ float sacc[8][512];   // 16 KB cross-wave reduce
    __shared__ float rd[512];
    __shared__ float s_z[8];

    // --- global softmax stats from 2048 (max, expsum) partials ---
    float m = -1e30f, e = 0.f;
    for (int i = t; i < 2048; i += 512) {
        float bm = ws[WS_PMAX + i], be = ws[WS_PEXP + i];
        float nm = fmaxf(m, bm);
        e = e * expf(m - nm) + be * expf(bm - nm);
        m = nm;
    }
    for (int o = 32; o > 0; o >>= 1) {
        float om = __shfl_xor(m, o), oe = __shfl_xor(e, o);
        float nm = fmaxf(m, om);
        e = e * expf(m - nm) + oe * expf(om - nm);
        m = nm;
    }
    if (lane == 0) { s_m[wv] = m; s_e[wv] = e; }
    __syncthreads();
    float mx = s_m[0];
    for (int i = 1; i < 8; ++i) mx = fmaxf(mx, s_m[i]);
    float Z = 0.f;
    for (int i = 0; i < 8; ++i) Z += s_e[i] * expf(s_m[i] - mx);
    const float invZ = 1.f / Z;
    const float g = sigm(ws[WS_ROUT + 513]);
    float a3 = ws[WS_ROUT + 514], b3 = ws[WS_ROUT + 515], c3 = ws[WS_ROUT + 516];
    float mm = fmaxf(a3, fmaxf(b3, c3));
    float ea = expf(a3 - mm), eb = expf(b3 - mm), ec = expf(c3 - mm);
    float ss = ea + eb + ec;
    const float s0 = ea / ss, s1 = eb / ss, s2 = ec / ss;
    const float gamma = 1.f + softplusf_(ws[WS_ROUT + 517]);

    // --- p for rows [b*256, b*256+256) ---
    const int start = b * 256;
    const float* sp = ws + WS_S;
    if (t < 258) {
        int idx = (start - 1 + t) & (NN - 1);
        wi_l[t] = g * rs[idx] + (1.f - g) * expf(sp[idx] - mx) * invZ;
    }
    __syncthreads();
    float ps = 0.f;
    if (t < 256) {
        float wsh = wi_l[t] * s0 + wi_l[t + 1] * s1 + wi_l[t + 2] * s2;
        float pv = powf(wsh, gamma);
        pl[t] = pv;
        ps = pv;
    }
    ps = wave_sum(ps);
    if (t < 256 && lane == 0) s_ps[wv] = ps;
    __syncthreads();
    if (t == 0) ast(ws + WS_PSUM + b, s_ps[0] + s_ps[1] + s_ps[2] + s_ps[3]);

    // --- bf16 partial column sums: wave wv sweeps rows wv, wv+8, ... (32 rows);
    //     lane covers 8 contiguous cols via one uint4 (16B) load per row ---
    {
        const unsigned short* wsb = (const unsigned short*)(ws + WS_BF);
        float a0 = 0.f, a1 = 0.f, a2 = 0.f, a3f = 0.f,
              a4 = 0.f, a5 = 0.f, a6 = 0.f, a7 = 0.f;
        #pragma unroll 4
        for (int r = wv; r < 256; r += 8) {
            float w = pl[r];
            uint4 q = *(const uint4*)(wsb + (size_t)(start + r) * 512 + lane * 8);
            a0 += w * __uint_as_float(q.x << 16);
            a1 += w * __uint_as_float(q.x & 0xFFFF0000u);
            a2 += w * __uint_as_float(q.y << 16);
            a3f += w * __uint_as_float(q.y & 0xFFFF0000u);
            a4 += w * __uint_as_float(q.z << 16);
            a5 += w * __uint_as_float(q.z & 0xFFFF0000u);
            a6 += w * __uint_as_float(q.w << 16);
            a7 += w * __uint_as_float(q.w & 0xFFFF0000u);
        }
        float* sw = &sacc[wv][lane * 8];
        sw[0] = a0; sw[1] = a1; sw[2] = a2; sw[3] = a3f;
        sw[4] = a4; sw[5] = a5; sw[6] = a6; sw[7] = a7;
    }
    __syncthreads();
    if (t < 256) {
        const int cc = t * 2;
        float u0 = 0.f, u1 = 0.f;
        #pragma unroll
        for (int w8 = 0; w8 < 8; ++w8) {
            u0 += sacc[w8][cc];
            u1 += sacc[w8][cc + 1];
        }
        ast2(ws + WS_PART + (size_t)b * 512 + cc, make_float2(u0, u1));
    }
    __syncthreads();
    if (t == 0) ast_rel(ws + WS_FLAGP + b, MAGIC);

    // ================= output phase: blocks 0..31 =================
    if (b >= 32) return;
    if (wv == 0) {
        int cap = 0;
        for (;;) {
            float v0 = ald_acq(ws + WS_FLAGP + lane);
            float v1 = ald_acq(ws + WS_FLAGP + 64 + lane);
            float v2 = ald_acq(ws + WS_FLAGP + 128 + lane);
            float v3 = ald_acq(ws + WS_FLAGP + 192 + lane);
            if (__all(v0 == MAGIC && v1 == MAGIC && v2 == MAGIC && v3 == MAGIC))
                break;
            __builtin_amdgcn_s_sleep(1);
            if (++cap > (1 << 20)) break;
        }
    }
    __syncthreads();
    float z = (t < 256) ? ald(ws + WS_PSUM + t) : 0.f;
    z = wave_sum(z);
    if (lane == 0) s_z[wv] = z;
    __syncthreads();
    float Zp = 0.f;
    for (int i = 0; i < 8; ++i) Zp += s_z[i];
    const float invZp = 1.f / (Zp + EPS);
    if (t < 256) {
        float ax = 0.f, ay = 0.f;
        const float* pp = ws + WS_PART + t * 2;
        #pragma unroll 16
        for (int r = 0; r < 256; ++r) {
            float2 v = ald2(pp + (size_t)r * 512);
            ax += v.x; ay += v.y;
        }
        rd[2 * t] = ax * invZp;
        rd[2 * t + 1] = ay * invZp;
    }
    __syncthreads();
    const int o = b * 8 + wv;
    const float* wo = W_out + (size_t)o * 1024;
    float a = dot4(ld4(wo + lane * 4), ld4(ws + WS_HNEW + lane * 4))
            + dot4(ld4(wo + 256 + lane * 4), ld4(ws + WS_HNEW + 256 + lane * 4))
            + dot4(ld4(wo + 512 + lane * 4), ld4(rd + lane * 4))
            + dot4(ld4(wo + 768 + lane * 4), ld4(rd + 256 + lane * 4));
    a = wave_sum(a);
    if (lane == 0) out[o] = sigm(a + b_out[o]);
}

extern "C" void kernel_launch(void* const* d_in, const int* in_sizes, int n_in,
                              void* d_out, int out_size, void* d_ws, size_t ws_size,
                              hipStream_t stream) {
    const float* x          = (const float*)d_in[0];
    const float* memory     = (const float*)d_in[1];
    const float* prev_read  = (const float*)d_in[2];
    const float* h          = (const float*)d_in[3];
    const float* c          = (const float*)d_in[4];
    const float* read_state = (const float*)d_in[5];
    // d_in[6] write_state, d_in[13] W_write, d_in[14] b_write: dead in reference
    const float* W_ih   = (const float*)d_in[7];
    const float* b_ih   = (const float*)d_in[8];
    const float* W_hh   = (const float*)d_in[9];
    const float* b_hh   = (const float*)d_in[10];
    const float* W_read = (const float*)d_in[11];
    const float* b_read = (const float*)d_in[12];
    const float* W_out  = (const float*)d_in[15];
    const float* b_out  = (const float*)d_in[16];
    float* ws  = (float*)d_ws;
    float* out = (float*)d_out;

    // DIAGNOSTIC ROUND: duplicate launches of deterministic/idempotent kernels
    // to extract per-kernel times from the dur_us delta vs R9 (76.6 us):
    //   dur(R10) - 76.6 = T(k_cos) + 2*T(k_readout)
    k_front<<<130, 256, 0, stream>>>(x, prev_read, h, c, W_ih, b_ih, W_hh, b_hh,
                                     W_read, b_read, ws);
    k_cos<<<2048, 256, 0, stream>>>(memory, ws);
    k_cos<<<2048, 256, 0, stream>>>(memory, ws);
    k_readout<<<256, 512, 0, stream>>>(read_state, W_out, b_out, ws, out);
    k_readout<<<256, 512, 0, stream>>>(read_state, W_out, b_out, ws, out);
    k_readout<<<256, 512, 0, stream>>>(read_state, W_out, b_out, ws, out);
}

// Round 11
// 77.567 us; speedup vs baseline: 2.1471x; 2.1471x over previous
//
#include <hip/hip_runtime.h>
#include <math.h>

#define EPS 1e-8f
#define NN 65536
#define MAGIC 1.0f

// ws float offsets
#define WS_GATES 0       // 2048
#define WS_HNEW  2048    // 512
#define WS_ROUT  2560    // 518 (pad 520)
#define WS_PMAX  3104    // 2048
#define WS_PEXP  5152    // 2048
#define WS_S     7200    // 65536
#define WS_PSUM  72736   // 256
#define WS_PART  72992   // 256*512 = 131072
#define WS_FLAGG 204064  // 128 gate-block flags
#define WS_FLAGP 204192  // 256 part-block flags
#define WS_BF    262144  // bf16 shadow of memory: 64 MB (as shorts)

__device__ __forceinline__ float wave_sum(float v) {
    for (int o = 32; o > 0; o >>= 1) v += __shfl_xor(v, o);
    return v;
}
__device__ __forceinline__ float sigm(float x) { return 1.f / (1.f + expf(-x)); }
__device__ __forceinline__ float softplusf_(float x) {
    return x > 20.f ? x : log1pf(expf(x));
}
__device__ __forceinline__ float dot4(float4 a, float4 b) {
    return a.x * b.x + a.y * b.y + a.z * b.z + a.w * b.w;
}
__device__ __forceinline__ float4 ld4(const float* p) { return *(const float4*)p; }

// agent-scope coherent accessors (R6/R8-proven on this chip)
__device__ __forceinline__ float ald(const float* p) {
    return __hip_atomic_load(p, __ATOMIC_RELAXED, __HIP_MEMORY_SCOPE_AGENT);
}
__device__ __forceinline__ float ald_acq(const float* p) {
    return __hip_atomic_load(p, __ATOMIC_ACQUIRE, __HIP_MEMORY_SCOPE_AGENT);
}
__device__ __forceinline__ void ast(float* p, float v) {
    __hip_atomic_store(p, v, __ATOMIC_RELAXED, __HIP_MEMORY_SCOPE_AGENT);
}
__device__ __forceinline__ void ast_rel(float* p, float v) {
    __hip_atomic_store(p, v, __ATOMIC_RELEASE, __HIP_MEMORY_SCOPE_AGENT);
}
__device__ __forceinline__ float2 ald2(const float* p) {
    unsigned long long u = __hip_atomic_load((const unsigned long long*)p,
        __ATOMIC_RELAXED, __HIP_MEMORY_SCOPE_AGENT);
    float2 r; __builtin_memcpy(&r, &u, 8); return r;
}
__device__ __forceinline__ void ast2(float* p, float2 v) {
    unsigned long long u; __builtin_memcpy(&u, &v, 8);
    __hip_atomic_store((unsigned long long*)p, u,
        __ATOMIC_RELAXED, __HIP_MEMORY_SCOPE_AGENT);
}

// pack two floats as RNE bf16 into one uint (a low short, b high short)
__device__ __forceinline__ unsigned bf2(float a, float b) {
    unsigned ua = __float_as_uint(a), ub = __float_as_uint(b);
    unsigned ra = (ua + 0x7FFFu + ((ua >> 16) & 1u)) >> 16;
    unsigned rb = (ub + 0x7FFFu + ((ub >> 16) & 1u)) >> 16;
    return ra | (rb << 16);
}

// K1: gates (blocks 0-127, 16 rows each) -> per-block flag -> h_new + r_out
__global__ __launch_bounds__(256) void k_front(const float* __restrict__ x,
                                               const float* __restrict__ pr,
                                               const float* __restrict__ h,
                                               const float* __restrict__ c,
                                               const float* __restrict__ W_ih,
                                               const float* __restrict__ b_ih,
                                               const float* __restrict__ W_hh,
                                               const float* __restrict__ b_hh,
                                               const float* __restrict__ W_read,
                                               const float* __restrict__ b_read,
                                               float* __restrict__ ws) {
    const int b = blockIdx.x, t = threadIdx.x;
    const int lane = t & 63, wv = t >> 6;
    __shared__ float sh[512];

    if (b < 128) {
        #pragma unroll
        for (int i = 0; i < 4; ++i) {
            const int row = b * 16 + wv * 4 + i;
            const float* wi = W_ih + (size_t)row * 768;
            const float* wh = W_hh + (size_t)row * 512;
            float acc = dot4(ld4(wi + lane * 4), ld4(x + lane * 4))
                      + dot4(ld4(wi + 256 + lane * 4), ld4(pr + lane * 4))
                      + dot4(ld4(wi + 512 + lane * 4), ld4(pr + 256 + lane * 4))
                      + dot4(ld4(wh + lane * 4), ld4(h + lane * 4))
                      + dot4(ld4(wh + 256 + lane * 4), ld4(h + 256 + lane * 4));
            acc = wave_sum(acc);
            if (lane == 0) ast(ws + WS_GATES + row, acc + b_ih[row] + b_hh[row]);
        }
        __syncthreads();
        if (t == 0) ast_rel(ws + WS_FLAGG + b, MAGIC);
    }

    if (wv == 0) {
        int cap = 0;
        for (;;) {
            float v0 = ald_acq(ws + WS_FLAGG + lane);
            float v1 = ald_acq(ws + WS_FLAGG + 64 + lane);
            if (__all(v0 == MAGIC && v1 == MAGIC)) break;
            __builtin_amdgcn_s_sleep(1);
            if (++cap > (1 << 20)) break;
        }
    }
    __syncthreads();

    for (int j = t; j < 512; j += 256) {
        float ig = ald(ws + WS_GATES + j);
        float fg = ald(ws + WS_GATES + 512 + j);
        float gg = ald(ws + WS_GATES + 1024 + j);
        float og = ald(ws + WS_GATES + 1536 + j);
        float cn = sigm(fg) * c[j] + sigm(ig) * tanhf(gg);
        float hn = sigm(og) * tanhf(cn);
        sh[j] = hn;
        if (b == 0) ws[WS_HNEW + j] = hn;
    }
    __syncthreads();
    const int o = b * 4 + wv;
    if (o < 518) {
        const float* wr = W_read + (size_t)o * 512;
        float acc = dot4(ld4(wr + lane * 4), ld4(sh + lane * 4))
                  + dot4(ld4(wr + 256 + lane * 4), ld4(sh + 256 + lane * 4));
        acc = wave_sum(acc);
        if (lane == 0) ws[WS_ROUT + o] = acc + b_read[o];
    }
}

// K2: cosine scores + bf16 shadow. REWRITE: 8 rows/wave straight-line,
// batched ILP-16 butterfly reduce, HW sqrt/rcp, fast exp.
__global__ __launch_bounds__(256, 4) void k_cos(const float* __restrict__ mem,
                                                float* __restrict__ ws) {
    const int t = threadIdx.x, lane = t & 63, wv = t >> 6;
    const int gw = blockIdx.x * 4 + wv;  // [0, 8192); rows n = gw + i*8192
    const float* key = ws + WS_ROUT;
    unsigned short* wsb = (unsigned short*)(ws + WS_BF);
    float4 ka = ld4(key + lane * 4);
    float4 kb = ld4(key + 256 + lane * 4);
    ka.x += EPS; ka.y += EPS; ka.z += EPS; ka.w += EPS;
    kb.x += EPS; kb.y += EPS; kb.z += EPS; kb.w += EPS;
    const float nb = fmaxf(__builtin_amdgcn_sqrtf(
                        wave_sum(dot4(ka, ka) + dot4(kb, kb))), EPS);
    const float beta = softplusf_(key[512]);
    float* sp = ws + WS_S;

    float d[8], q[8];
    // two groups of 4 rows to bound VGPR pressure
    #pragma unroll
    for (int grp = 0; grp < 2; ++grp) {
        float4 va[4], vb[4];
        #pragma unroll
        for (int i = 0; i < 4; ++i) {
            const size_t n = (size_t)gw + (grp * 4 + i) * 8192;
            va[i] = ld4(mem + n * 512 + lane * 4);
            vb[i] = ld4(mem + n * 512 + 256 + lane * 4);
        }
        #pragma unroll
        for (int i = 0; i < 4; ++i) {
            const size_t n = (size_t)gw + (grp * 4 + i) * 8192;
            uint2 p0 = make_uint2(bf2(va[i].x, va[i].y), bf2(va[i].z, va[i].w));
            uint2 p1 = make_uint2(bf2(vb[i].x, vb[i].y), bf2(vb[i].z, vb[i].w));
            *(uint2*)(wsb + n * 512 + lane * 4) = p0;
            *(uint2*)(wsb + n * 512 + 256 + lane * 4) = p1;
            va[i].x += EPS; va[i].y += EPS; va[i].z += EPS; va[i].w += EPS;
            vb[i].x += EPS; vb[i].y += EPS; vb[i].z += EPS; vb[i].w += EPS;
            d[grp * 4 + i] = dot4(va[i], ka) + dot4(vb[i], kb);
            q[grp * 4 + i] = dot4(va[i], va[i]) + dot4(vb[i], vb[i]);
        }
    }
    // single ILP-16 butterfly (depth 6 for all 8 rows' dot+sq)
    #pragma unroll
    for (int o = 32; o > 0; o >>= 1) {
        #pragma unroll
        for (int i = 0; i < 8; ++i) {
            d[i] += __shfl_xor(d[i], o);
            q[i] += __shfl_xor(q[i], o);
        }
    }
    float sv[8];
    #pragma unroll
    for (int i = 0; i < 8; ++i) {
        float na = fmaxf(__builtin_amdgcn_sqrtf(q[i]), EPS);
        sv[i] = beta * d[i] * __builtin_amdgcn_rcpf(na * nb);
    }
    // store: lane i writes sv[i] (values wave-uniform after butterfly)
    {
        float mysv = sv[0];
        #pragma unroll
        for (int i = 1; i < 8; ++i) if (lane == i) mysv = sv[i];
        if (lane < 8) sp[gw + lane * 8192] = mysv;
    }
    // per-wave (max, expsum) over the 8 rows, tree + ILP exps
    float m01 = fmaxf(sv[0], sv[1]), m23 = fmaxf(sv[2], sv[3]);
    float m45 = fmaxf(sv[4], sv[5]), m67 = fmaxf(sv[6], sv[7]);
    float m = fmaxf(fmaxf(m01, m23), fmaxf(m45, m67));
    float e = 0.f;
    #pragma unroll
    for (int i = 0; i < 8; ++i) e += __expf(sv[i] - m);

    __shared__ float sm[4], se[4];
    if (lane == 0) { sm[wv] = m; se[wv] = e; }
    __syncthreads();
    if (t == 0) {
        float M = fmaxf(fmaxf(sm[0], sm[1]), fmaxf(sm[2], sm[3]));
        float E = se[0] * __expf(sm[0] - M) + se[1] * __expf(sm[1] - M) +
                  se[2] * __expf(sm[2] - M) + se[3] * __expf(sm[3] - M);
        ws[WS_PMAX + blockIdx.x] = M;
        ws[WS_PEXP + blockIdx.x] = E;
    }
}

// K3: stats + p + bf16 partial column sums -> flag -> blocks 0..31 output phase
__global__ __launch_bounds__(512) void k_readout(const float* __restrict__ rs,
                                                 const float* __restrict__ W_out,
                                                 const float* __restrict__ b_out,
                                                 float* __restrict__ ws,
                                                 float* __restrict__ out) {
    const int b = blockIdx.x, t = threadIdx.x;
    const int lane = t & 63, wv = t >> 6;
    __shared__ float s_m[8], s_e[8];
    __shared__ float wi_l[258];
    __shared__ float pl[256];
    __shared__ float s_ps[4];
    __shared__ float sacc[8][512];
    __shared__ float rd[512];
    __shared__ float s_z[8];

    float m = -1e30f, e = 0.f;
    for (int i = t; i < 2048; i += 512) {
        float bm = ws[WS_PMAX + i], be = ws[WS_PEXP + i];
        float nm = fmaxf(m, bm);
        e = e * expf(m - nm) + be * expf(bm - nm);
        m = nm;
    }
    for (int o = 32; o > 0; o >>= 1) {
        float om = __shfl_xor(m, o), oe = __shfl_xor(e, o);
        float nm = fmaxf(m, om);
        e = e * expf(m - nm) + oe * expf(om - nm);
        m = nm;
    }
    if (lane == 0) { s_m[wv] = m; s_e[wv] = e; }
    __syncthreads();
    float mx = s_m[0];
    for (int i = 1; i < 8; ++i) mx = fmaxf(mx, s_m[i]);
    float Z = 0.f;
    for (int i = 0; i < 8; ++i) Z += s_e[i] * expf(s_m[i] - mx);
    const float invZ = 1.f / Z;
    const float g = sigm(ws[WS_ROUT + 513]);
    float a3 = ws[WS_ROUT + 514], b3 = ws[WS_ROUT + 515], c3 = ws[WS_ROUT + 516];
    float mm = fmaxf(a3, fmaxf(b3, c3));
    float ea = expf(a3 - mm), eb = expf(b3 - mm), ec = expf(c3 - mm);
    float ss = ea + eb + ec;
    const float s0 = ea / ss, s1 = eb / ss, s2 = ec / ss;
    const float gamma = 1.f + softplusf_(ws[WS_ROUT + 517]);

    const int start = b * 256;
    const float* sp = ws + WS_S;
    if (t < 258) {
        int idx = (start - 1 + t) & (NN - 1);
        wi_l[t] = g * rs[idx] + (1.f - g) * expf(sp[idx] - mx) * invZ;
    }
    __syncthreads();
    float ps = 0.f;
    if (t < 256) {
        float wsh = wi_l[t] * s0 + wi_l[t + 1] * s1 + wi_l[t + 2] * s2;
        float pv = powf(wsh, gamma);
        pl[t] = pv;
        ps = pv;
    }
    ps = wave_sum(ps);
    if (t < 256 && lane == 0) s_ps[wv] = ps;
    __syncthreads();
    if (t == 0) ast(ws + WS_PSUM + b, s_ps[0] + s_ps[1] + s_ps[2] + s_ps[3]);

    {
        const unsigned short* wsb = (const unsigned short*)(ws + WS_BF);
        float a0 = 0.f, a1 = 0.f, a2 = 0.f, a3f = 0.f,
              a4 = 0.f, a5 = 0.f, a6 = 0.f, a7 = 0.f;
        #pragma unroll 4
        for (int r = wv; r < 256; r += 8) {
            float w = pl[r];
            uint4 qv = *(const uint4*)(wsb + (size_t)(start + r) * 512 + lane * 8);
            a0 += w * __uint_as_float(qv.x << 16);
            a1 += w * __uint_as_float(qv.x & 0xFFFF0000u);
            a2 += w * __uint_as_float(qv.y << 16);
            a3f += w * __uint_as_float(qv.y & 0xFFFF0000u);
            a4 += w * __uint_as_float(qv.z << 16);
            a5 += w * __uint_as_float(qv.z & 0xFFFF0000u);
            a6 += w * __uint_as_float(qv.w << 16);
            a7 += w * __uint_as_float(qv.w & 0xFFFF0000u);
        }
        float* sw = &sacc[wv][lane * 8];
        sw[0] = a0; sw[1] = a1; sw[2] = a2; sw[3] = a3f;
        sw[4] = a4; sw[5] = a5; sw[6] = a6; sw[7] = a7;
    }
    __syncthreads();
    if (t < 256) {
        const int cc = t * 2;
        float u0 = 0.f, u1 = 0.f;
        #pragma unroll
        for (int w8 = 0; w8 < 8; ++w8) {
            u0 += sacc[w8][cc];
            u1 += sacc[w8][cc + 1];
        }
        ast2(ws + WS_PART + (size_t)b * 512 + cc, make_float2(u0, u1));
    }
    __syncthreads();
    if (t == 0) ast_rel(ws + WS_FLAGP + b, MAGIC);

    if (b >= 32) return;
    if (wv == 0) {
        int cap = 0;
        for (;;) {
            float v0 = ald_acq(ws + WS_FLAGP + lane);
            float v1 = ald_acq(ws + WS_FLAGP + 64 + lane);
            float v2 = ald_acq(ws + WS_FLAGP + 128 + lane);
            float v3 = ald_acq(ws + WS_FLAGP + 192 + lane);
            if (__all(v0 == MAGIC && v1 == MAGIC && v2 == MAGIC && v3 == MAGIC))
                break;
            __builtin_amdgcn_s_sleep(1);
            if (++cap > (1 << 20)) break;
        }
    }
    __syncthreads();
    float z = (t < 256) ? ald(ws + WS_PSUM + t) : 0.f;
    z = wave_sum(z);
    if (lane == 0) s_z[wv] = z;
    __syncthreads();
    float Zp = 0.f;
    for (int i = 0; i < 8; ++i) Zp += s_z[i];
    const float invZp = 1.f / (Zp + EPS);
    if (t < 256) {
        float ax = 0.f, ay = 0.f;
        const float* pp = ws + WS_PART + t * 2;
        #pragma unroll 16
        for (int r = 0; r < 256; ++r) {
            float2 v = ald2(pp + (size_t)r * 512);
            ax += v.x; ay += v.y;
        }
        rd[2 * t] = ax * invZp;
        rd[2 * t + 1] = ay * invZp;
    }
    __syncthreads();
    const int o = b * 8 + wv;
    const float* wo = W_out + (size_t)o * 1024;
    float a = dot4(ld4(wo + lane * 4), ld4(ws + WS_HNEW + lane * 4))
            + dot4(ld4(wo + 256 + lane * 4), ld4(ws + WS_HNEW + 256 + lane * 4))
            + dot4(ld4(wo + 512 + lane * 4), ld4(rd + lane * 4))
            + dot4(ld4(wo + 768 + lane * 4), ld4(rd + 256 + lane * 4));
    a = wave_sum(a);
    if (lane == 0) out[o] = sigm(a + b_out[o]);
}

extern "C" void kernel_launch(void* const* d_in, const int* in_sizes, int n_in,
                              void* d_out, int out_size, void* d_ws, size_t ws_size,
                              hipStream_t stream) {
    const float* x          = (const float*)d_in[0];
    const float* memory     = (const float*)d_in[1];
    const float* prev_read  = (const float*)d_in[2];
    const float* h          = (const float*)d_in[3];
    const float* c          = (const float*)d_in[4];
    const float* read_state = (const float*)d_in[5];
    // d_in[6] write_state, d_in[13] W_write, d_in[14] b_write: dead in reference
    const float* W_ih   = (const float*)d_in[7];
    const float* b_ih   = (const float*)d_in[8];
    const float* W_hh   = (const float*)d_in[9];
    const float* b_hh   = (const float*)d_in[10];
    const float* W_read = (const float*)d_in[11];
    const float* b_read = (const float*)d_in[12];
    const float* W_out  = (const float*)d_in[15];
    const float* b_out  = (const float*)d_in[16];
    float* ws  = (float*)d_ws;
    float* out = (float*)d_out;

    k_front<<<130, 256, 0, stream>>>(x, prev_read, h, c, W_ih, b_ih, W_hh, b_hh,
                                     W_read, b_read, ws);
    k_cos<<<2048, 256, 0, stream>>>(memory, ws);
    k_readout<<<256, 512, 0, stream>>>(read_state, W_out, b_out, ws, out);
}

// Round 12
// 76.011 us; speedup vs baseline: 2.1911x; 1.0205x over previous
//
#include <hip/hip_runtime.h>
#include <math.h>

#define EPS 1e-8f
#define NN 65536
#define MAGIC 1.0f

// ws float offsets
#define WS_GATES 0       // 2048
#define WS_HNEW  2048    // 512
#define WS_ROUT  2560    // 518 (pad 520)
#define WS_PMAX  3104    // 2048
#define WS_PEXP  5152    // 2048
#define WS_S     7200    // 65536
#define WS_PSUM  72736   // 256
#define WS_PART  72992   // 256*512 = 131072
#define WS_FLAGG 204064  // 128 gate-block flags
#define WS_FLAGP 204192  // 256 part-block flags
#define WS_PART2 204448  // 32*512 = 16384
#define WS_FLAG2 220832  // 32 stage-2 flags
#define WS_BF    262144  // bf16 shadow of memory: 64 MB (as shorts)

__device__ __forceinline__ float wave_sum(float v) {
    for (int o = 32; o > 0; o >>= 1) v += __shfl_xor(v, o);
    return v;
}
__device__ __forceinline__ float sigm(float x) { return 1.f / (1.f + expf(-x)); }
__device__ __forceinline__ float softplusf_(float x) {
    return x > 20.f ? x : log1pf(expf(x));
}
__device__ __forceinline__ float dot4(float4 a, float4 b) {
    return a.x * b.x + a.y * b.y + a.z * b.z + a.w * b.w;
}
__device__ __forceinline__ float4 ld4(const float* p) { return *(const float4*)p; }

// agent-scope accessors: used ONLY for flags (+ k_front's GATES exchange)
__device__ __forceinline__ float ald(const float* p) {
    return __hip_atomic_load(p, __ATOMIC_RELAXED, __HIP_MEMORY_SCOPE_AGENT);
}
__device__ __forceinline__ float ald_acq(const float* p) {
    return __hip_atomic_load(p, __ATOMIC_ACQUIRE, __HIP_MEMORY_SCOPE_AGENT);
}
__device__ __forceinline__ void ast(float* p, float v) {
    __hip_atomic_store(p, v, __ATOMIC_RELAXED, __HIP_MEMORY_SCOPE_AGENT);
}
__device__ __forceinline__ void ast_rel(float* p, float v) {
    __hip_atomic_store(p, v, __ATOMIC_RELEASE, __HIP_MEMORY_SCOPE_AGENT);
}

// pack two floats as RNE bf16 into one uint (a low short, b high short)
__device__ __forceinline__ unsigned bf2(float a, float b) {
    unsigned ua = __float_as_uint(a), ub = __float_as_uint(b);
    unsigned ra = (ua + 0x7FFFu + ((ua >> 16) & 1u)) >> 16;
    unsigned rb = (ub + 0x7FFFu + ((ub >> 16) & 1u)) >> 16;
    return ra | (rb << 16);
}

// K1: gates (blocks 0-127, 16 rows each) -> per-block flag -> h_new + r_out
__global__ __launch_bounds__(256) void k_front(const float* __restrict__ x,
                                               const float* __restrict__ pr,
                                               const float* __restrict__ h,
                                               const float* __restrict__ c,
                                               const float* __restrict__ W_ih,
                                               const float* __restrict__ b_ih,
                                               const float* __restrict__ W_hh,
                                               const float* __restrict__ b_hh,
                                               const float* __restrict__ W_read,
                                               const float* __restrict__ b_read,
                                               float* __restrict__ ws) {
    const int b = blockIdx.x, t = threadIdx.x;
    const int lane = t & 63, wv = t >> 6;
    __shared__ float sh[512];

    if (b < 128) {
        #pragma unroll
        for (int i = 0; i < 4; ++i) {
            const int row = b * 16 + wv * 4 + i;
            const float* wi = W_ih + (size_t)row * 768;
            const float* wh = W_hh + (size_t)row * 512;
            float acc = dot4(ld4(wi + lane * 4), ld4(x + lane * 4))
                      + dot4(ld4(wi + 256 + lane * 4), ld4(pr + lane * 4))
                      + dot4(ld4(wi + 512 + lane * 4), ld4(pr + 256 + lane * 4))
                      + dot4(ld4(wh + lane * 4), ld4(h + lane * 4))
                      + dot4(ld4(wh + 256 + lane * 4), ld4(h + 256 + lane * 4));
            acc = wave_sum(acc);
            if (lane == 0) ast(ws + WS_GATES + row, acc + b_ih[row] + b_hh[row]);
        }
        __syncthreads();
        if (t == 0) ast_rel(ws + WS_FLAGG + b, MAGIC);
    }

    if (wv == 0) {
        int cap = 0;
        for (;;) {
            float v0 = ald_acq(ws + WS_FLAGG + lane);
            float v1 = ald_acq(ws + WS_FLAGG + 64 + lane);
            if (__all(v0 == MAGIC && v1 == MAGIC)) break;
            __builtin_amdgcn_s_sleep(1);
            if (++cap > (1 << 20)) break;
        }
    }
    __syncthreads();

    for (int j = t; j < 512; j += 256) {
        float ig = ald(ws + WS_GATES + j);
        float fg = ald(ws + WS_GATES + 512 + j);
        float gg = ald(ws + WS_GATES + 1024 + j);
        float og = ald(ws + WS_GATES + 1536 + j);
        float cn = sigm(fg) * c[j] + sigm(ig) * tanhf(gg);
        float hn = sigm(og) * tanhf(cn);
        sh[j] = hn;
        if (b == 0) ws[WS_HNEW + j] = hn;
    }
    __syncthreads();
    const int o = b * 4 + wv;
    if (o < 518) {
        const float* wr = W_read + (size_t)o * 512;
        float acc = dot4(ld4(wr + lane * 4), ld4(sh + lane * 4))
                  + dot4(ld4(wr + 256 + lane * 4), ld4(sh + 256 + lane * 4));
        acc = wave_sum(acc);
        if (lane == 0) ws[WS_ROUT + o] = acc + b_read[o];
    }
}

// K2: cosine scores + bf16 shadow. 8 rows/wave in two groups of 4,
// SOFTWARE-PIPELINED: group g+1's loads issued before group g's reduce.
// No launch_bounds occupancy cap (R11 lesson: (256,4) caps VGPR at 64 -> spills).
__global__ __launch_bounds__(256) void k_cos(const float* __restrict__ mem,
                                             float* __restrict__ ws) {
    const int t = threadIdx.x, lane = t & 63, wv = t >> 6;
    const int gw = blockIdx.x * 4 + wv;  // [0,8192); rows n = gw + i*8192
    const float* key = ws + WS_ROUT;
    unsigned short* wsb = (unsigned short*)(ws + WS_BF);
    float4 ka = ld4(key + lane * 4);
    float4 kb = ld4(key + 256 + lane * 4);
    ka.x += EPS; ka.y += EPS; ka.z += EPS; ka.w += EPS;
    kb.x += EPS; kb.y += EPS; kb.z += EPS; kb.w += EPS;
    const float nb = fmaxf(__builtin_amdgcn_sqrtf(
                        wave_sum(dot4(ka, ka) + dot4(kb, kb))), EPS);
    const float beta = softplusf_(key[512]);
    float* sp = ws + WS_S;

    float4 va[4], vb[4], xa[4], xb[4];
    #pragma unroll
    for (int i = 0; i < 4; ++i) {
        const size_t n = (size_t)gw + i * 8192;
        va[i] = ld4(mem + n * 512 + lane * 4);
        vb[i] = ld4(mem + n * 512 + 256 + lane * 4);
    }
    #pragma unroll
    for (int i = 0; i < 4; ++i) {   // next group in flight during grp0 compute
        const size_t n = (size_t)gw + (4 + i) * 8192;
        xa[i] = ld4(mem + n * 512 + lane * 4);
        xb[i] = ld4(mem + n * 512 + 256 + lane * 4);
    }

    float m = -1e30f, e = 0.f;
    #pragma unroll
    for (int grp = 0; grp < 2; ++grp) {
        float d[4], q[4];
        #pragma unroll
        for (int i = 0; i < 4; ++i) {
            const size_t n = (size_t)gw + (grp * 4 + i) * 8192;
            *(uint2*)(wsb + n * 512 + lane * 4) =
                make_uint2(bf2(va[i].x, va[i].y), bf2(va[i].z, va[i].w));
            *(uint2*)(wsb + n * 512 + 256 + lane * 4) =
                make_uint2(bf2(vb[i].x, vb[i].y), bf2(vb[i].z, vb[i].w));
            float4 wa = va[i], wb = vb[i];
            wa.x += EPS; wa.y += EPS; wa.z += EPS; wa.w += EPS;
            wb.x += EPS; wb.y += EPS; wb.z += EPS; wb.w += EPS;
            d[i] = dot4(wa, ka) + dot4(wb, kb);
            q[i] = dot4(wa, wa) + dot4(wb, wb);
        }
        if (grp == 0) {  // rotate pipeline before the latency-heavy reduce
            #pragma unroll
            for (int i = 0; i < 4; ++i) { va[i] = xa[i]; vb[i] = xb[i]; }
        }
        #pragma unroll
        for (int o = 32; o > 0; o >>= 1) {
            #pragma unroll
            for (int i = 0; i < 4; ++i) {
                d[i] += __shfl_xor(d[i], o);
                q[i] += __shfl_xor(q[i], o);
            }
        }
        float sv[4];
        #pragma unroll
        for (int i = 0; i < 4; ++i) {
            float na = fmaxf(__builtin_amdgcn_sqrtf(q[i]), EPS);
            sv[i] = beta * d[i] * __builtin_amdgcn_rcpf(na * nb);
        }
        float mysv = sv[0];
        if (lane == 1) mysv = sv[1];
        if (lane == 2) mysv = sv[2];
        if (lane == 3) mysv = sv[3];
        if (lane < 4) sp[gw + (grp * 4 + lane) * 8192] = mysv;
        float gm = fmaxf(fmaxf(sv[0], sv[1]), fmaxf(sv[2], sv[3]));
        float nm = fmaxf(m, gm);
        e = e * __expf(m - nm) + __expf(sv[0] - nm) + __expf(sv[1] - nm)
          + __expf(sv[2] - nm) + __expf(sv[3] - nm);
        m = nm;
    }

    __shared__ float sm[4], se[4];
    if (lane == 0) { sm[wv] = m; se[wv] = e; }
    __syncthreads();
    if (t == 0) {
        float M = fmaxf(fmaxf(sm[0], sm[1]), fmaxf(sm[2], sm[3]));
        float E = se[0] * __expf(sm[0] - M) + se[1] * __expf(sm[1] - M) +
                  se[2] * __expf(sm[2] - M) + se[3] * __expf(sm[3] - M);
        ws[WS_PMAX + blockIdx.x] = M;
        ws[WS_PEXP + blockIdx.x] = E;
    }
}

// K3: stats + p + bf16 partial column sums (plain mem ops, release-flag) ->
//     blocks 0..31: two-stage PART reduce + output.
__global__ __launch_bounds__(512) void k_readout(const float* __restrict__ rs,
                                                 const float* __restrict__ W_out,
                                                 const float* __restrict__ b_out,
                                                 float* __restrict__ ws,
                                                 float* __restrict__ out) {
    const int b = blockIdx.x, t = threadIdx.x;
    const int lane = t & 63, wv = t >> 6;
    __shared__ float s_m[8], s_e[8];
    __shared__ float wi_l[258];
    __shared__ float pl[256];
    __shared__ float s_ps[4];
    __shared__ float sacc[8][512];
    __shared__ float rd[512];
    __shared__ float s_z[8];

    // --- global softmax stats from 2048 (max, expsum) partials (plain reads;
    //     produced by k_cos, visible across the kernel boundary) ---
    float m = -1e30f, e = 0.f;
    for (int i = t; i < 2048; i += 512) {
        float bm = ws[WS_PMAX + i], be = ws[WS_PEXP + i];
        float nm = fmaxf(m, bm);
        e = e * expf(m - nm) + be * expf(bm - nm);
        m = nm;
    }
    for (int o = 32; o > 0; o >>= 1) {
        float om = __shfl_xor(m, o), oe = __shfl_xor(e, o);
        float nm = fmaxf(m, om);
        e = e * expf(m - nm) + oe * expf(om - nm);
        m = nm;
    }
    if (lane == 0) { s_m[wv] = m; s_e[wv] = e; }
    __syncthreads();
    float mx = s_m[0];
    for (int i = 1; i < 8; ++i) mx = fmaxf(mx, s_m[i]);
    float Z = 0.f;
    for (int i = 0; i < 8; ++i) Z += s_e[i] * expf(s_m[i] - mx);
    const float invZ = 1.f / Z;
    const float g = sigm(ws[WS_ROUT + 513]);
    float a3 = ws[WS_ROUT + 514], b3 = ws[WS_ROUT + 515], c3 = ws[WS_ROUT + 516];
    float mm = fmaxf(a3, fmaxf(b3, c3));
    float ea = expf(a3 - mm), eb = expf(b3 - mm), ec = expf(c3 - mm);
    float ss = ea + eb + ec;
    const float s0 = ea / ss, s1 = eb / ss, s2 = ec / ss;
    const float gamma = 1.f + softplusf_(ws[WS_ROUT + 517]);

    // --- p for rows [b*256, b*256+256) ---
    const int start = b * 256;
    const float* sp = ws + WS_S;
    if (t < 258) {
        int idx = (start - 1 + t) & (NN - 1);
        wi_l[t] = g * rs[idx] + (1.f - g) * expf(sp[idx] - mx) * invZ;
    }
    __syncthreads();
    float ps = 0.f;
    if (t < 256) {
        float wsh = wi_l[t] * s0 + wi_l[t + 1] * s1 + wi_l[t + 2] * s2;
        float pv = powf(wsh, gamma);
        pl[t] = pv;
        ps = pv;
    }
    ps = wave_sum(ps);
    if (t < 256 && lane == 0) s_ps[wv] = ps;
    __syncthreads();
    if (t == 0) ws[WS_PSUM + b] = s_ps[0] + s_ps[1] + s_ps[2] + s_ps[3];

    // --- bf16 partial column sums (plain uint4 loads; plain stores) ---
    {
        const unsigned short* wsb = (const unsigned short*)(ws + WS_BF);
        float a0 = 0.f, a1 = 0.f, a2 = 0.f, a3f = 0.f,
              a4 = 0.f, a5 = 0.f, a6 = 0.f, a7 = 0.f;
        #pragma unroll 4
        for (int r = wv; r < 256; r += 8) {
            float w = pl[r];
            uint4 qv = *(const uint4*)(wsb + (size_t)(start + r) * 512 + lane * 8);
            a0 += w * __uint_as_float(qv.x << 16);
            a1 += w * __uint_as_float(qv.x & 0xFFFF0000u);
            a2 += w * __uint_as_float(qv.y << 16);
            a3f += w * __uint_as_float(qv.y & 0xFFFF0000u);
            a4 += w * __uint_as_float(qv.z << 16);
            a5 += w * __uint_as_float(qv.z & 0xFFFF0000u);
            a6 += w * __uint_as_float(qv.w << 16);
            a7 += w * __uint_as_float(qv.w & 0xFFFF0000u);
        }
        float* sw = &sacc[wv][lane * 8];
        sw[0] = a0; sw[1] = a1; sw[2] = a2; sw[3] = a3f;
        sw[4] = a4; sw[5] = a5; sw[6] = a6; sw[7] = a7;
    }
    __syncthreads();
    if (t < 256) {
        const int cc = t * 2;
        float u0 = 0.f, u1 = 0.f;
        #pragma unroll
        for (int w8 = 0; w8 < 8; ++w8) {
            u0 += sacc[w8][cc];
            u1 += sacc[w8][cc + 1];
        }
        *(float2*)(ws + WS_PART + (size_t)b * 512 + cc) = make_float2(u0, u1);
    }
    __syncthreads();
    if (t == 0) ast_rel(ws + WS_FLAGP + b, MAGIC);  // release: publishes PART+PSUM

    // ================= output phase: blocks 0..31 =================
    if (b >= 32) return;
    if (wv == 0) {
        int cap = 0;
        for (;;) {
            float v0 = ald_acq(ws + WS_FLAGP + lane);
            float v1 = ald_acq(ws + WS_FLAGP + 64 + lane);
            float v2 = ald_acq(ws + WS_FLAGP + 128 + lane);
            float v3 = ald_acq(ws + WS_FLAGP + 192 + lane);
            if (__all(v0 == MAGIC && v1 == MAGIC && v2 == MAGIC && v3 == MAGIC))
                break;
            __builtin_amdgcn_s_sleep(1);
            if (++cap > (1 << 20)) break;
        }
    }
    __syncthreads();
    // stage 1: PART2[b][col] = sum of PART rows [8b, 8b+8)   (plain ops)
    {
        float s = 0.f;
        #pragma unroll
        for (int r = 0; r < 8; ++r)
            s += ws[WS_PART + (size_t)(8 * b + r) * 512 + t];
        ws[WS_PART2 + (size_t)b * 512 + t] = s;
    }
    __syncthreads();
    if (t == 0) ast_rel(ws + WS_FLAG2 + b, MAGIC);
    if (wv == 0) {
        int cap = 0;
        for (;;) {
            float v = ald_acq(ws + WS_FLAG2 + (lane & 31));
            if (__all(v == MAGIC)) break;
            __builtin_amdgcn_s_sleep(1);
            if (++cap > (1 << 20)) break;
        }
    }
    __syncthreads();
    // Zp + rd
    float z = (t < 256) ? ws[WS_PSUM + t] : 0.f;
    z = wave_sum(z);
    if (lane == 0) s_z[wv] = z;
    __syncthreads();
    float Zp = 0.f;
    for (int i = 0; i < 8; ++i) Zp += s_z[i];
    const float invZp = 1.f / (Zp + EPS);
    if (t < 256) {
        float ax = 0.f, ay = 0.f;
        #pragma unroll 8
        for (int r = 0; r < 32; ++r) {
            float2 v = *(const float2*)(ws + WS_PART2 + (size_t)r * 512 + t * 2);
            ax += v.x; ay += v.y;
        }
        rd[2 * t] = ax * invZp;
        rd[2 * t + 1] = ay * invZp;
    }
    __syncthreads();
    const int o = b * 8 + wv;
    const float* wo = W_out + (size_t)o * 1024;
    float a = dot4(ld4(wo + lane * 4), ld4(ws + WS_HNEW + lane * 4))
            + dot4(ld4(wo + 256 + lane * 4), ld4(ws + WS_HNEW + 256 + lane * 4))
            + dot4(ld4(wo + 512 + lane * 4), ld4(rd + lane * 4))
            + dot4(ld4(wo + 768 + lane * 4), ld4(rd + 256 + lane * 4));
    a = wave_sum(a);
    if (lane == 0) out[o] = sigm(a + b_out[o]);
}

extern "C" void kernel_launch(void* const* d_in, const int* in_sizes, int n_in,
                              void* d_out, int out_size, void* d_ws, size_t ws_size,
                              hipStream_t stream) {
    const float* x          = (const float*)d_in[0];
    const float* memory     = (const float*)d_in[1];
    const float* prev_read  = (const float*)d_in[2];
    const float* h          = (const float*)d_in[3];
    const float* c          = (const float*)d_in[4];
    const float* read_state = (const float*)d_in[5];
    // d_in[6] write_state, d_in[13] W_write, d_in[14] b_write: dead in reference
    const float* W_ih   = (const float*)d_in[7];
    const float* b_ih   = (const float*)d_in[8];
    const float* W_hh   = (const float*)d_in[9];
    const float* b_hh   = (const float*)d_in[10];
    const float* W_read = (const float*)d_in[11];
    const float* b_read = (const float*)d_in[12];
    const float* W_out  = (const float*)d_in[15];
    const float* b_out  = (const float*)d_in[16];
    float* ws  = (float*)d_ws;
    float* out = (float*)d_out;

    k_front<<<130, 256, 0, stream>>>(x, prev_read, h, c, W_ih, b_ih, W_hh, b_hh,
                                     W_read, b_read, ws);
    k_cos<<<2048, 256, 0, stream>>>(memory, ws);
    k_readout<<<256, 512, 0, stream>>>(read_state, W_out, b_out, ws, out);
}